// Round 11
// baseline (799.850 us; speedup 1.0000x reference)
//
#include <hip/hip_runtime.h>

#define NF 481
#define NT 500
#define CH 16
#define HID 32
#define NB 16
#define NSEQ (NB*NF)   // 7696

typedef __attribute__((ext_vector_type(8))) short short8;
typedef __attribute__((ext_vector_type(4))) float f32x4;

union S8U4 { short8 s; uint4 u; };

// fast sigmoid — v_rcp instead of correctly-rounded divide (R10 win)
__device__ __forceinline__ float sig_(float v) {
    return __builtin_amdgcn_rcpf(1.0f + __expf(-v));
}
// sigmoid for PRE-SCALED logits: v = log2e * x  ->  1/(1+2^-v).
__device__ __forceinline__ float sige_(float v) {
    float e;
    asm("v_exp_f32 %0, -%1" : "=v"(e) : "v"(v));
    return __builtin_amdgcn_rcpf(1.0f + e);
}

__device__ __forceinline__ unsigned short f2bf(float f) {
    unsigned u = __float_as_uint(f);
    u = (u + 0x7fffu + ((u >> 16) & 1u)) >> 16;   // RNE
    return (unsigned short)u;
}
__device__ __forceinline__ unsigned int pk2(float a, float b) {
    return (unsigned int)f2bf(a) | ((unsigned int)f2bf(b) << 16);
}
__device__ __forceinline__ float bf2f(short s) {
    return __uint_as_float(((unsigned)(unsigned short)s) << 16);
}
__device__ __forceinline__ float4 prelu4(float4 v, float a) {
    v.x = (v.x >= 0.f) ? v.x : a*v.x;
    v.y = (v.y >= 0.f) ? v.y : a*v.y;
    v.z = (v.z >= 0.f) ? v.z : a*v.z;
    v.w = (v.w >= 0.f) ? v.w : a*v.w;
    return v;
}

#define FMA4(Q, W, V)                     \
    Q.x = fmaf((W), (V).x, Q.x);          \
    Q.y = fmaf((W), (V).y, Q.y);          \
    Q.z = fmaf((W), (V).z, Q.z);          \
    Q.w = fmaf((W), (V).w, Q.w)

// -------------------------------------------------------------------------
// Pass 1: conv1(4->16,k9,p4) + PReLU -> y1 (b,f,t,ch) bf16.  (R9 verbatim)
// -------------------------------------------------------------------------
#define P1TAP(D, K1)                                                           \
    {                                                                          \
        const int gf = f + (K1) - 4;                                           \
        if (gf >= 0 && gf < NF) {                                              \
            const float4 v = *(const float4*)(feat +                           \
                ((size_t)(b*4 + (D))*NF + gf)*NT + tc0);                       \
            FMA4(q0,  w1[ 0*36 + (D)*9 + (K1)], v);                            \
            FMA4(q1,  w1[ 1*36 + (D)*9 + (K1)], v);                            \
            FMA4(q2,  w1[ 2*36 + (D)*9 + (K1)], v);                            \
            FMA4(q3,  w1[ 3*36 + (D)*9 + (K1)], v);                            \
            FMA4(q4,  w1[ 4*36 + (D)*9 + (K1)], v);                            \
            FMA4(q5,  w1[ 5*36 + (D)*9 + (K1)], v);                            \
            FMA4(q6,  w1[ 6*36 + (D)*9 + (K1)], v);                            \
            FMA4(q7,  w1[ 7*36 + (D)*9 + (K1)], v);                            \
            FMA4(q8,  w1[ 8*36 + (D)*9 + (K1)], v);                            \
            FMA4(q9,  w1[ 9*36 + (D)*9 + (K1)], v);                            \
            FMA4(q10, w1[10*36 + (D)*9 + (K1)], v);                            \
            FMA4(q11, w1[11*36 + (D)*9 + (K1)], v);                            \
            FMA4(q12, w1[12*36 + (D)*9 + (K1)], v);                            \
            FMA4(q13, w1[13*36 + (D)*9 + (K1)], v);                            \
            FMA4(q14, w1[14*36 + (D)*9 + (K1)], v);                            \
            FMA4(q15, w1[15*36 + (D)*9 + (K1)], v);                            \
        }                                                                      \
    }

#define STX(OP, E, COMP)                                                       \
    *(uint4*)((OP) + (E)*CH) = make_uint4(                                     \
        pk2(q0.COMP, q1.COMP),  pk2(q2.COMP, q3.COMP),                         \
        pk2(q4.COMP, q5.COMP),  pk2(q6.COMP, q7.COMP));                        \
    *(uint4*)((OP) + (E)*CH + 8) = make_uint4(                                 \
        pk2(q8.COMP, q9.COMP),  pk2(q10.COMP, q11.COMP),                       \
        pk2(q12.COMP, q13.COMP), pk2(q14.COMP, q15.COMP))

__global__ __launch_bounds__(256) void conv1_kernel(
    const float* __restrict__ feat,
    const float* __restrict__ w1, const float* __restrict__ b1, const float* __restrict__ a1p,
    unsigned short* __restrict__ y1)          // (b, f, t, ch) bf16
{
    const int b    = blockIdx.x;
    const int wv   = threadIdx.x >> 6;
    const int lane = threadIdx.x & 63;
    const int f    = blockIdx.y*4 + wv;
    if (f >= NF) return;
    const int gt0  = blockIdx.z*256 + lane*4;
    const int tc0  = (gt0 <= NT-4) ? gt0 : (NT-4);
    const float al1 = a1p[0];

    float4 q0  = make_float4(b1[0],b1[0],b1[0],b1[0]);
    float4 q1  = make_float4(b1[1],b1[1],b1[1],b1[1]);
    float4 q2  = make_float4(b1[2],b1[2],b1[2],b1[2]);
    float4 q3  = make_float4(b1[3],b1[3],b1[3],b1[3]);
    float4 q4  = make_float4(b1[4],b1[4],b1[4],b1[4]);
    float4 q5  = make_float4(b1[5],b1[5],b1[5],b1[5]);
    float4 q6  = make_float4(b1[6],b1[6],b1[6],b1[6]);
    float4 q7  = make_float4(b1[7],b1[7],b1[7],b1[7]);
    float4 q8  = make_float4(b1[8],b1[8],b1[8],b1[8]);
    float4 q9  = make_float4(b1[9],b1[9],b1[9],b1[9]);
    float4 q10 = make_float4(b1[10],b1[10],b1[10],b1[10]);
    float4 q11 = make_float4(b1[11],b1[11],b1[11],b1[11]);
    float4 q12 = make_float4(b1[12],b1[12],b1[12],b1[12]);
    float4 q13 = make_float4(b1[13],b1[13],b1[13],b1[13]);
    float4 q14 = make_float4(b1[14],b1[14],b1[14],b1[14]);
    float4 q15 = make_float4(b1[15],b1[15],b1[15],b1[15]);

    #pragma unroll
    for (int d = 0; d < 4; d++) {
        P1TAP(d, 0); P1TAP(d, 1); P1TAP(d, 2); P1TAP(d, 3); P1TAP(d, 4);
        P1TAP(d, 5); P1TAP(d, 6); P1TAP(d, 7); P1TAP(d, 8);
    }

    if (gt0 < NT) {
        q0  = prelu4(q0,  al1); q1  = prelu4(q1,  al1);
        q2  = prelu4(q2,  al1); q3  = prelu4(q3,  al1);
        q4  = prelu4(q4,  al1); q5  = prelu4(q5,  al1);
        q6  = prelu4(q6,  al1); q7  = prelu4(q7,  al1);
        q8  = prelu4(q8,  al1); q9  = prelu4(q9,  al1);
        q10 = prelu4(q10, al1); q11 = prelu4(q11, al1);
        q12 = prelu4(q12, al1); q13 = prelu4(q13, al1);
        q14 = prelu4(q14, al1); q15 = prelu4(q15, al1);
        unsigned short* op = y1 + ((size_t)(b*NF + f)*NT + gt0)*CH;
        STX(op, 0, x); STX(op, 1, y); STX(op, 2, z); STX(op, 3, w);
    }
}

// -------------------------------------------------------------------------
// Pass 2: conv2(16->16,k5,p2) via MFMA + PReLU -> x (n,t,16).  (R9 verbatim)
// -------------------------------------------------------------------------
__global__ __launch_bounds__(256) void conv2_kernel(
    const unsigned short* __restrict__ y1,    // (b, f, t, ch) bf16
    const float* __restrict__ w2, const float* __restrict__ b2, const float* __restrict__ a2p,
    unsigned short* __restrict__ xout)
{
    __shared__ unsigned short ylds[8*128*24];    // 48 KB: [row8][t128][ch16+pad8]
    const int b    = blockIdx.x;
    const int f0   = blockIdx.y * 4;
    const int tg   = blockIdx.z * 128;
    const int tid  = threadIdx.x;
    const int wid  = tid >> 6;
    const int lane = tid & 63;

    #pragma unroll
    for (int i = 0; i < 8; i++) {
        const int idx  = tid + i*256;        // 0..2047
        const int row  = idx >> 8;           // 0..7
        const int tt   = (idx >> 1) & 127;
        const int half = idx & 1;
        const int fr   = f0 - 2 + row;
        const int gt   = tg + tt;
        uint4 v = make_uint4(0u, 0u, 0u, 0u);
        if (fr >= 0 && fr < NF && gt < NT)
            v = *(const uint4*)(y1 + ((size_t)(b*NF + fr)*NT + gt)*CH + half*8);
        *(uint4*)&ylds[(row*128 + tt)*24 + half*8] = v;
    }
    __syncthreads();

    const int c    = lane & 15;
    const int quad = lane >> 4;
    const int f    = f0 + wid;
    if (f < NF) {
        const float al2 = a2p[0];
        short8 Bh0, Bh1, Bh2, Bl0, Bl1, Bl2;
        #define MKB2(BH, BL, Q)                                                \
            { _Pragma("unroll") for (int j = 0; j < 8; j++) {                  \
                const int ci = (quad & 1)*8 + j;                               \
                const int kk = 2*(Q) + (quad >> 1);                            \
                float w = 0.f;                                                 \
                if (kk < 5) w = w2[c*80 + ci*5 + kk];                          \
                const unsigned short hb = f2bf(w);                             \
                const float hf = bf2f((short)hb);                              \
                BH[j] = (short)hb;                                             \
                BL[j] = (short)f2bf(w - hf); } }
        MKB2(Bh0, Bl0, 0); MKB2(Bh1, Bl1, 1); MKB2(Bh2, Bl2, 2);
        #undef MKB2

        // bias per ROW: acc[r] is cout = quad*4 + r
        const f32x4 cb = {b2[quad*4 + 0], b2[quad*4 + 1],
                          b2[quad*4 + 2], b2[quad*4 + 3]};
        const int ci0 = (quad & 1)*8;
        const int r0  = wid + (quad >> 1);
        unsigned short* xo = xout + ((size_t)(b*NF + f)*NT)*CH + quad*4;

        #pragma unroll
        for (int ti = 0; ti < 8; ti++) {
            const int t = ti*16 + c;             // B col = t within the 128-slice
            const int rl2 = (r0 + 4 > 7) ? 7 : (r0 + 4);
            const short8 a0 = *(const short8*)&ylds[((r0    )*128 + t)*24 + ci0];
            const short8 a1 = *(const short8*)&ylds[((r0 + 2)*128 + t)*24 + ci0];
            const short8 a2 = *(const short8*)&ylds[((rl2   )*128 + t)*24 + ci0];
            f32x4 acc = cb;
            acc = __builtin_amdgcn_mfma_f32_16x16x32_bf16(Bl0, a0, acc, 0, 0, 0);
            acc = __builtin_amdgcn_mfma_f32_16x16x32_bf16(Bl1, a1, acc, 0, 0, 0);
            acc = __builtin_amdgcn_mfma_f32_16x16x32_bf16(Bl2, a2, acc, 0, 0, 0);
            acc = __builtin_amdgcn_mfma_f32_16x16x32_bf16(Bh0, a0, acc, 0, 0, 0);
            acc = __builtin_amdgcn_mfma_f32_16x16x32_bf16(Bh1, a1, acc, 0, 0, 0);
            acc = __builtin_amdgcn_mfma_f32_16x16x32_bf16(Bh2, a2, acc, 0, 0, 0);
            const int tt = tg + t;
            if (tt < NT) {
                float v0 = acc[0], v1 = acc[1], v2 = acc[2], v3 = acc[3];
                v0 = (v0 >= 0.f) ? v0 : al2*v0;
                v1 = (v1 >= 0.f) ? v1 : al2*v1;
                v2 = (v2 >= 0.f) ? v2 : al2*v2;
                v3 = (v3 >= 0.f) ? v3 : al2*v3;
                *(uint2*)(xo + (size_t)tt*CH) = make_uint2(pk2(v0, v1), pk2(v2, v3));
            }
        }
    }
}

// -------------------------------------------------------------------------
// GRU — R11: R10's all-register operand-swapped structure + in-wave DUAL
// GROUP (32 seqs/wave).  R6's dual-group failed because its critical path
// was LDS turnaround between wave_barriers (duplicates, doesn't fill); the
// R10 loop is pure register MFMA+VALU with ZERO barriers/ds-ops, so group
// B's ~620 issue cycles slot into group A's ~770 latency-stall cycles.
// W fragments and bias C-vectors are lane-indexed -> SHARED between groups.
// -------------------------------------------------------------------------
__global__ __launch_bounds__(64) void gru_kernel(
    const unsigned short* __restrict__ xin,  // (NSEQ, NT, 16) bf16
    const float* __restrict__ h0,    // (NSEQ, 32)
    const float* __restrict__ w_ih,  // (96, 16)
    const float* __restrict__ w_hh,  // (96, 32)
    const float* __restrict__ b_ih, const float* __restrict__ b_hh,
    const float* __restrict__ fc_w, const float* __restrict__ fc_b,
    float* __restrict__ prob,        // (NSEQ, NT)
    float* __restrict__ hout)        // (NSEQ, 32)
{
    const int lane = threadIdx.x & 63;
    const int c    = lane & 15;
    const int quad = lane >> 4;
    const int baseA = blockIdx.x * 32;       // 241 blocks x 32 seq
    const int baseB = (baseA + 16 <= NSEQ - 16) ? (baseA + 16) : (NSEQ - 16);
    const float L2E = 1.4426950408889634f;

    // reader-side unit base (this lane's owned units = U(quad))
    const int ub = (quad == 0) ? 16 : (quad == 1) ? 24 : (quad == 2) ? 0 : 8;
    // builder-side unit mapping (W-frag row = c): g_A(c) = U(c>>2)[c&3]
    const int cq  = c >> 2;
    const int ubr = (cq == 0) ? 16 : (cq == 1) ? 24 : (cq == 2) ? 0 : 8;
    const int uA  = ubr + (c & 3);
    const int uB  = uA + 4;

    // ---- W fragments (srcA: row = c -> gate of unit uA/uB, k = quad*8+j) ----
    #define BLDR(DST, CK, GROW)                                                \
        { _Pragma("unroll") for (int j = 0; j < 8; j++) {                      \
            const int k = (CK)*32 + quad*8 + j;                                \
            float wv_ = 0.f;                                                   \
            if (k < 16)      wv_ = w_ih[(GROW)*16 + k];                        \
            else if (k < 48) wv_ = w_hh[(GROW)*32 + k - 16];                   \
            DST[j] = (short)f2bf(wv_ * L2E); } }
    #define BLDX(DST, U)                                                       \
        { _Pragma("unroll") for (int j = 0; j < 8; j++) {                      \
            const int k = quad*8 + j;                                          \
            float wv_ = (k < 16) ? w_ih[(64+(U))*16 + k] : 0.f;                \
            DST[j] = (short)f2bf(wv_ * 2.f*L2E); } }
    #define BLDH(DST, CK, U)                                                   \
        { _Pragma("unroll") for (int j = 0; j < 8; j++) {                      \
            const int k = (CK)*32 + quad*8 + j;                                \
            float wv_ = (k >= 16 && k < 48) ? w_hh[(64+(U))*32 + k - 16] : 0.f;\
            DST[j] = (short)f2bf(wv_ * 2.f*L2E); } }
    #define BLDF(DST, CK)                                                      \
        { _Pragma("unroll") for (int j = 0; j < 8; j++) {                      \
            const int k = (CK)*32 + quad*8 + j;                                \
            float wv_ = (k >= 16 && k < 48) ? fc_w[k - 16] : 0.f;              \
            DST[j] = (short)f2bf(wv_); } }

    short8 WRaA, WRbA, WRaB, WRbB;
    short8 WZaA, WZbA, WZaB, WZbB;
    short8 WXaA, WXaB;
    short8 WHaA, WHbA, WHaB, WHbB;
    short8 WFa, WFb;
    BLDR(WRaA, 0, uA);     BLDR(WRbA, 1, uA);
    BLDR(WRaB, 0, uB);     BLDR(WRbB, 1, uB);
    BLDR(WZaA, 0, 32+uA);  BLDR(WZbA, 1, 32+uA);
    BLDR(WZaB, 0, 32+uB);  BLDR(WZbB, 1, 32+uB);
    BLDX(WXaA, uA);        BLDX(WXaB, uB);
    BLDH(WHaA, 0, uA);     BLDH(WHbA, 1, uA);
    BLDH(WHaB, 0, uB);     BLDH(WHbB, 1, uB);
    BLDF(WFa, 0);          BLDF(WFb, 1);

    // ---- per-row biases as MFMA C (shared between groups) ----
    const float4 biA = *(const float4*)(b_ih + ub);
    const float4 biB = *(const float4*)(b_ih + ub + 4);
    const float4 bhA = *(const float4*)(b_hh + ub);
    const float4 bhB = *(const float4*)(b_hh + ub + 4);
    const float4 ziA = *(const float4*)(b_ih + 32 + ub);
    const float4 ziB = *(const float4*)(b_ih + 36 + ub);
    const float4 zhA = *(const float4*)(b_hh + 32 + ub);
    const float4 zhB = *(const float4*)(b_hh + 36 + ub);
    const float4 niA = *(const float4*)(b_ih + 64 + ub);
    const float4 niB = *(const float4*)(b_ih + 68 + ub);
    const float4 nhA = *(const float4*)(b_hh + 64 + ub);
    const float4 nhB = *(const float4*)(b_hh + 68 + ub);
    const f32x4 cbRA = {(biA.x+bhA.x)*L2E, (biA.y+bhA.y)*L2E, (biA.z+bhA.z)*L2E, (biA.w+bhA.w)*L2E};
    const f32x4 cbRB = {(biB.x+bhB.x)*L2E, (biB.y+bhB.y)*L2E, (biB.z+bhB.z)*L2E, (biB.w+bhB.w)*L2E};
    const f32x4 cbZA = {(ziA.x+zhA.x)*L2E, (ziA.y+zhA.y)*L2E, (ziA.z+zhA.z)*L2E, (ziA.w+zhA.w)*L2E};
    const f32x4 cbZB = {(ziB.x+zhB.x)*L2E, (ziB.y+zhB.y)*L2E, (ziB.z+zhB.z)*L2E, (ziB.w+zhB.w)*L2E};
    const f32x4 cbXA = {niA.x*2.f*L2E, niA.y*2.f*L2E, niA.z*2.f*L2E, niA.w*2.f*L2E};
    const f32x4 cbXB = {niB.x*2.f*L2E, niB.y*2.f*L2E, niB.z*2.f*L2E, niB.w*2.f*L2E};
    const f32x4 cbHA = {nhA.x*2.f*L2E, nhA.y*2.f*L2E, nhA.z*2.f*L2E, nhA.w*2.f*L2E};
    const f32x4 cbHB = {nhB.x*2.f*L2E, nhB.y*2.f*L2E, nhB.z*2.f*L2E, nhB.w*2.f*L2E};
    const float fb = fc_b[0];
    const f32x4 cbF = {fb, fb, fb, fb};

    // ---- h state: 8 fp32 regs per group ----
    const float* hrA = h0 + (size_t)(baseA + c)*HID + ub;
    const float* hrB = h0 + (size_t)(baseB + c)*HID + ub;
    float hA0 = hrA[0], hA1 = hrA[1], hA2 = hrA[2], hA3 = hrA[3];
    float hA4 = hrA[4], hA5 = hrA[5], hA6 = hrA[6], hA7 = hrA[7];
    float hB0 = hrB[0], hB1 = hrB[1], hB2 = hrB[2], hB3 = hrB[3];
    float hB4 = hrB[4], hB5 = hrB[5], hB6 = hrB[6], hB7 = hrB[7];

    // ---- x pointers + 3-deep prefetch per group ----
    const unsigned short* xpA = xin + ((size_t)(baseA + c)*NT)*CH + (quad & 1)*8;
    const unsigned short* xpB = xin + ((size_t)(baseB + c)*NT)*CH + (quad & 1)*8;
    uint4 xcA = *(const uint4*)(xpA);
    uint4 n1A = *(const uint4*)(xpA + 1*CH);
    uint4 n2A = *(const uint4*)(xpA + 2*CH);
    uint4 xcB = *(const uint4*)(xpB);
    uint4 n1B = *(const uint4*)(xpB + 1*CH);
    uint4 n2B = *(const uint4*)(xpB + 2*CH);

    const short8 zero8 = {0,0,0,0,0,0,0,0};

    #define PACKH(HA, H0,H1,H2,H3,H4,H5,H6,H7)                                 \
        { unsigned p0_, p1_, p2_, p3_;                                         \
          asm("v_cvt_pk_bf16_f32 %0, %1, %2" : "=v"(p0_) : "v"(H0), "v"(H1));  \
          asm("v_cvt_pk_bf16_f32 %0, %1, %2" : "=v"(p1_) : "v"(H2), "v"(H3));  \
          asm("v_cvt_pk_bf16_f32 %0, %1, %2" : "=v"(p2_) : "v"(H4), "v"(H5));  \
          asm("v_cvt_pk_bf16_f32 %0, %1, %2" : "=v"(p3_) : "v"(H6), "v"(H7));  \
          S8U4 hu_; hu_.u = make_uint4(p0_, p1_, p2_, p3_);                    \
          HA = hu_.s; }

    #define GS(ACR, ACZ, ACX, ACH, R, HREG)                                    \
        {                                                                      \
            const float rr = sige_(ACR[R]);                                    \
            const float zz = sige_(ACZ[R]);                                    \
            const float aa = fmaf(rr, ACH[R], ACX[R]);                         \
            const float nn = fmaf(2.f, sige_(aa), -1.f);                       \
            HREG = fmaf(zz, HREG - nn, nn);                                    \
        }

    for (int t = 0; t < NT; t++) {
        short8 haA; PACKH(haA, hA0,hA1,hA2,hA3,hA4,hA5,hA6,hA7);
        short8 haB; PACKH(haB, hB0,hB1,hB2,hB3,hB4,hB5,hB6,hB7);
        S8U4 xuA; xuA.u = xcA;
        S8U4 xuB; xuB.u = xcB;
        const short8 a0A = (quad < 2) ? xuA.s : haA;
        const short8 a1A = (quad < 2) ? haA   : zero8;
        const short8 a0B = (quad < 2) ? xuB.s : haB;
        const short8 a1B = (quad < 2) ? haB   : zero8;

        // prefetch x(t+3) both groups
        const int tn = (t + 3 < NT) ? t + 3 : NT - 1;
        const uint4 fxA = *(const uint4*)(xpA + (size_t)tn*CH);
        const uint4 fxB = *(const uint4*)(xpB + (size_t)tn*CH);

        f32x4 aRA = __builtin_amdgcn_mfma_f32_16x16x32_bf16(WRaA, a0A, cbRA, 0, 0, 0);
        f32x4 bRA = __builtin_amdgcn_mfma_f32_16x16x32_bf16(WRaA, a0B, cbRA, 0, 0, 0);
        f32x4 aRB = __builtin_amdgcn_mfma_f32_16x16x32_bf16(WRaB, a0A, cbRB, 0, 0, 0);
        f32x4 bRB = __builtin_amdgcn_mfma_f32_16x16x32_bf16(WRaB, a0B, cbRB, 0, 0, 0);
        f32x4 aZA = __builtin_amdgcn_mfma_f32_16x16x32_bf16(WZaA, a0A, cbZA, 0, 0, 0);
        f32x4 bZA = __builtin_amdgcn_mfma_f32_16x16x32_bf16(WZaA, a0B, cbZA, 0, 0, 0);
        f32x4 aZB = __builtin_amdgcn_mfma_f32_16x16x32_bf16(WZaB, a0A, cbZB, 0, 0, 0);
        f32x4 bZB = __builtin_amdgcn_mfma_f32_16x16x32_bf16(WZaB, a0B, cbZB, 0, 0, 0);
        f32x4 aXA = __builtin_amdgcn_mfma_f32_16x16x32_bf16(WXaA, a0A, cbXA, 0, 0, 0);
        f32x4 bXA = __builtin_amdgcn_mfma_f32_16x16x32_bf16(WXaA, a0B, cbXA, 0, 0, 0);
        f32x4 aXB = __builtin_amdgcn_mfma_f32_16x16x32_bf16(WXaB, a0A, cbXB, 0, 0, 0);
        f32x4 bXB = __builtin_amdgcn_mfma_f32_16x16x32_bf16(WXaB, a0B, cbXB, 0, 0, 0);
        f32x4 aHA = __builtin_amdgcn_mfma_f32_16x16x32_bf16(WHaA, a0A, cbHA, 0, 0, 0);
        f32x4 bHA = __builtin_amdgcn_mfma_f32_16x16x32_bf16(WHaA, a0B, cbHA, 0, 0, 0);
        f32x4 aHB = __builtin_amdgcn_mfma_f32_16x16x32_bf16(WHaB, a0A, cbHB, 0, 0, 0);
        f32x4 bHB = __builtin_amdgcn_mfma_f32_16x16x32_bf16(WHaB, a0B, cbHB, 0, 0, 0);
        f32x4 aF  = __builtin_amdgcn_mfma_f32_16x16x32_bf16(WFa,  a0A, cbF,  0, 0, 0);
        f32x4 bF  = __builtin_amdgcn_mfma_f32_16x16x32_bf16(WFa,  a0B, cbF,  0, 0, 0);
        aRA = __builtin_amdgcn_mfma_f32_16x16x32_bf16(WRbA, a1A, aRA, 0, 0, 0);
        bRA = __builtin_amdgcn_mfma_f32_16x16x32_bf16(WRbA, a1B, bRA, 0, 0, 0);
        aRB = __builtin_amdgcn_mfma_f32_16x16x32_bf16(WRbB, a1A, aRB, 0, 0, 0);
        bRB = __builtin_amdgcn_mfma_f32_16x16x32_bf16(WRbB, a1B, bRB, 0, 0, 0);
        aZA = __builtin_amdgcn_mfma_f32_16x16x32_bf16(WZbA, a1A, aZA, 0, 0, 0);
        bZA = __builtin_amdgcn_mfma_f32_16x16x32_bf16(WZbA, a1B, bZA, 0, 0, 0);
        aZB = __builtin_amdgcn_mfma_f32_16x16x32_bf16(WZbB, a1A, aZB, 0, 0, 0);
        bZB = __builtin_amdgcn_mfma_f32_16x16x32_bf16(WZbB, a1B, bZB, 0, 0, 0);
        aHA = __builtin_amdgcn_mfma_f32_16x16x32_bf16(WHbA, a1A, aHA, 0, 0, 0);
        bHA = __builtin_amdgcn_mfma_f32_16x16x32_bf16(WHbA, a1B, bHA, 0, 0, 0);
        aHB = __builtin_amdgcn_mfma_f32_16x16x32_bf16(WHbB, a1A, aHB, 0, 0, 0);
        bHB = __builtin_amdgcn_mfma_f32_16x16x32_bf16(WHbB, a1B, bHB, 0, 0, 0);
        aF  = __builtin_amdgcn_mfma_f32_16x16x32_bf16(WFb,  a1A, aF,  0, 0, 0);
        bF  = __builtin_amdgcn_mfma_f32_16x16x32_bf16(WFb,  a1B, bF,  0, 0, 0);

        if (t > 0 && lane < 16) {
            prob[(size_t)(baseA + c)*NT + (t - 1)] = sig_(aF[0]);
            prob[(size_t)(baseB + c)*NT + (t - 1)] = sig_(bF[0]);
        }

        GS(aRA, aZA, aXA, aHA, 0, hA0);
        GS(bRA, bZA, bXA, bHA, 0, hB0);
        GS(aRA, aZA, aXA, aHA, 1, hA1);
        GS(bRA, bZA, bXA, bHA, 1, hB1);
        GS(aRA, aZA, aXA, aHA, 2, hA2);
        GS(bRA, bZA, bXA, bHA, 2, hB2);
        GS(aRA, aZA, aXA, aHA, 3, hA3);
        GS(bRA, bZA, bXA, bHA, 3, hB3);
        GS(aRB, aZB, aXB, aHB, 0, hA4);
        GS(bRB, bZB, bXB, bHB, 0, hB4);
        GS(aRB, aZB, aXB, aHB, 1, hA5);
        GS(bRB, bZB, bXB, bHB, 1, hB5);
        GS(aRB, aZB, aXB, aHB, 2, hA6);
        GS(bRB, bZB, bXB, bHB, 2, hB6);
        GS(aRB, aZB, aXB, aHB, 3, hA7);
        GS(bRB, bZB, bXB, bHB, 3, hB7);

        xcA = n1A; n1A = n2A; n2A = fxA;
        xcB = n1B; n1B = n2B; n2B = fxB;
    }

    // final prob (FC on h(NT)) for both groups
    {
        short8 haA; PACKH(haA, hA0,hA1,hA2,hA3,hA4,hA5,hA6,hA7);
        short8 haB; PACKH(haB, hB0,hB1,hB2,hB3,hB4,hB5,hB6,hB7);
        const short8 a0A = (quad < 2) ? zero8 : haA;
        const short8 a1A = (quad < 2) ? haA   : zero8;
        const short8 a0B = (quad < 2) ? zero8 : haB;
        const short8 a1B = (quad < 2) ? haB   : zero8;
        f32x4 aF = __builtin_amdgcn_mfma_f32_16x16x32_bf16(WFa, a0A, cbF, 0, 0, 0);
        f32x4 bF = __builtin_amdgcn_mfma_f32_16x16x32_bf16(WFa, a0B, cbF, 0, 0, 0);
        aF = __builtin_amdgcn_mfma_f32_16x16x32_bf16(WFb, a1A, aF, 0, 0, 0);
        bF = __builtin_amdgcn_mfma_f32_16x16x32_bf16(WFb, a1B, bF, 0, 0, 0);
        if (lane < 16) {
            prob[(size_t)(baseA + c)*NT + (NT - 1)] = sig_(aF[0]);
            prob[(size_t)(baseB + c)*NT + (NT - 1)] = sig_(bF[0]);
        }
    }

    // hout: each lane writes its 8 units of both groups' seq (base+c)
    float* hoA = hout + (size_t)(baseA + c)*HID + ub;
    float* hoB = hout + (size_t)(baseB + c)*HID + ub;
    *(float4*)(hoA)     = make_float4(hA0, hA1, hA2, hA3);
    *(float4*)(hoA + 4) = make_float4(hA4, hA5, hA6, hA7);
    *(float4*)(hoB)     = make_float4(hB0, hB1, hB2, hB3);
    *(float4*)(hoB + 4) = make_float4(hB4, hB5, hB6, hB7);
}

// -------------------------------------------------------------------------
extern "C" void kernel_launch(void* const* d_in, const int* in_sizes, int n_in,
                              void* d_out, int out_size, void* d_ws, size_t ws_size,
                              hipStream_t stream)
{
    const float* feat = (const float*)d_in[0];
    const float* h0   = (const float*)d_in[1];
    const float* w1   = (const float*)d_in[2];
    const float* b1   = (const float*)d_in[3];
    const float* a1   = (const float*)d_in[4];
    const float* w2   = (const float*)d_in[5];
    const float* b2   = (const float*)d_in[6];
    const float* a2   = (const float*)d_in[7];
    const float* wih  = (const float*)d_in[8];
    const float* whh  = (const float*)d_in[9];
    const float* bih  = (const float*)d_in[10];
    const float* bhh  = (const float*)d_in[11];
    const float* fcw  = (const float*)d_in[12];
    const float* fcb  = (const float*)d_in[13];

    unsigned short* xbuf = (unsigned short*)d_ws;            // 123.1 MB bf16
    unsigned short* y1   = xbuf + (size_t)NSEQ*NT*CH;        // 123.1 MB bf16 (b,f,t,ch)
    float* prob = (float*)d_out;                             // (B, F, T)
    float* hout = prob + (size_t)NSEQ*NT;                    // (1, NSEQ, 32)

    dim3 c1grid(NB, 121, 2);                                 // 4 f-waves x 256 t
    conv1_kernel<<<c1grid, 256, 0, stream>>>(feat, w1, b1, a1, y1);
    dim3 c2grid(NB, 121, 4);                                 // 4 f x 128 t per block
    conv2_kernel<<<c2grid, 256, 0, stream>>>(y1, w2, b2, a2, xbuf);
    gru_kernel<<<(NSEQ + 31)/32, 64, 0, stream>>>(xbuf, h0, wih, whh, bih, bhh, fcw, fcb, prob, hout);
}

// Round 12
// 548.920 us; speedup vs baseline: 1.4571x; 1.4571x over previous
//
#include <hip/hip_runtime.h>

#define NF 481
#define NT 500
#define CH 16
#define HID 32
#define NB 16
#define NSEQ (NB*NF)   // 7696

typedef __attribute__((ext_vector_type(8))) short short8;
typedef __attribute__((ext_vector_type(4))) float f32x4;

union S8U4 { short8 s; uint4 u; };

// fast sigmoid — v_rcp instead of correctly-rounded divide
__device__ __forceinline__ float sig_(float v) {
    return __builtin_amdgcn_rcpf(1.0f + __expf(-v));
}
// sigmoid for PRE-SCALED logits: v = log2e * x  ->  1/(1+2^-v).
__device__ __forceinline__ float sige_(float v) {
    float e;
    asm("v_exp_f32 %0, -%1" : "=v"(e) : "v"(v));
    return __builtin_amdgcn_rcpf(1.0f + e);
}

__device__ __forceinline__ unsigned short f2bf(float f) {
    unsigned u = __float_as_uint(f);
    u = (u + 0x7fffu + ((u >> 16) & 1u)) >> 16;   // RNE
    return (unsigned short)u;
}
__device__ __forceinline__ unsigned int pk2(float a, float b) {
    return (unsigned int)f2bf(a) | ((unsigned int)f2bf(b) << 16);
}
__device__ __forceinline__ float bf2f(short s) {
    return __uint_as_float(((unsigned)(unsigned short)s) << 16);
}

// -------------------------------------------------------------------------
// Pass 1 (R12): conv1(4->16,k9,p4) + PReLU -> y1 (b,f,t,ch) bf16 via MFMA.
// Clone of the proven conv2-R9 structure.  K = 36 taps, k = kk*4 + d:
// chunk0 = kk 0..7 (32 taps), chunk1 = kk 8 (4 taps, rest zero).
// feat fp32 -> hi/lo bf16 staged in LDS [12 rows][128 t][4 d]; weights
// hi/lo; acc = Whi*Dhi + Whi*Dlo + Wlo*Dhi (dropped Wlo*Dlo ~ 2^-16).
// D layout row=ch, col=t -> uint2 stores (4 consecutive ch per lane).
// Replaces 2304 fp32 VALU FMAs/lane (issue-bound, 18% IPC) with 48 MFMAs
// + 48 ds_read_b64 per wave.
// -------------------------------------------------------------------------
__global__ __launch_bounds__(256) void conv1_kernel(
    const float* __restrict__ feat,
    const float* __restrict__ w1, const float* __restrict__ b1, const float* __restrict__ a1p,
    unsigned short* __restrict__ y1)          // (b, f, t, ch) bf16
{
    __shared__ unsigned short fhi[12*128*4];  // 12 KB  [row][t][d]
    __shared__ unsigned short flo[12*128*4];  // 12 KB
    const int b    = blockIdx.x;
    const int f0   = blockIdx.y * 4;
    const int tg   = blockIdx.z * 128;
    const int tid  = threadIdx.x;
    const int wid  = tid >> 6;
    const int lane = tid & 63;
    const int c    = lane & 15;
    const int quad = lane >> 4;

    // ---- stage: rows f0-4 .. f0+7 (zero outside f-range), hi/lo bf16 ----
    #pragma unroll
    for (int i = 0; i < 6; i++) {
        const int row = i*2 + (tid >> 7);     // 0..11
        const int tt  = tid & 127;
        const int gf  = f0 - 4 + row;
        const int gt  = (tg + tt < NT) ? (tg + tt) : (NT - 1);
        float v0 = 0.f, v1 = 0.f, v2 = 0.f, v3 = 0.f;
        if (gf >= 0 && gf < NF) {
            v0 = feat[((size_t)(b*4 + 0)*NF + gf)*NT + gt];
            v1 = feat[((size_t)(b*4 + 1)*NF + gf)*NT + gt];
            v2 = feat[((size_t)(b*4 + 2)*NF + gf)*NT + gt];
            v3 = feat[((size_t)(b*4 + 3)*NF + gf)*NT + gt];
        }
        unsigned ph01, ph23;
        asm("v_cvt_pk_bf16_f32 %0, %1, %2" : "=v"(ph01) : "v"(v0), "v"(v1));
        asm("v_cvt_pk_bf16_f32 %0, %1, %2" : "=v"(ph23) : "v"(v2), "v"(v3));
        const float h0f = __uint_as_float(ph01 << 16);
        const float h1f = __uint_as_float(ph01 & 0xffff0000u);
        const float h2f = __uint_as_float(ph23 << 16);
        const float h3f = __uint_as_float(ph23 & 0xffff0000u);
        unsigned pl01, pl23;
        asm("v_cvt_pk_bf16_f32 %0, %1, %2" : "=v"(pl01) : "v"(v0 - h0f), "v"(v1 - h1f));
        asm("v_cvt_pk_bf16_f32 %0, %1, %2" : "=v"(pl23) : "v"(v2 - h2f), "v"(v3 - h3f));
        *(uint2*)&fhi[(row*128 + tt)*4] = make_uint2(ph01, ph23);
        *(uint2*)&flo[(row*128 + tt)*4] = make_uint2(pl01, pl23);
    }
    __syncthreads();

    const int f = f0 + wid;

    // ---- weight fragments (srcA row = c = ch, k = quad*8 + j) ----
    short8 Whi0, Wlo0, Whi1, Wlo1;
    { _Pragma("unroll") for (int j = 0; j < 8; j++) {
        // chunk0: kk = quad*2 + (j>>2), d = j&3
        {
            const int kk = quad*2 + (j >> 2);
            const int d  = j & 3;
            const float w = w1[c*36 + d*9 + kk];
            const unsigned short hb = f2bf(w);
            Whi0[j] = (short)hb;
            Wlo0[j] = (short)f2bf(w - bf2f((short)hb));
        }
        // chunk1: kk = 8 + quad*2 + (j>>2) -> valid only kk==8 (quad 0, j<4)
        {
            float w = 0.f;
            if (quad == 0 && j < 4) w = w1[c*36 + (j & 3)*9 + 8];
            const unsigned short hb = f2bf(w);
            Whi1[j] = (short)hb;
            Wlo1[j] = (short)f2bf(w - bf2f((short)hb));
        }
    } }

    const float al1 = a1p[0];
    const f32x4 cb = {b1[quad*4 + 0], b1[quad*4 + 1],
                      b1[quad*4 + 2], b1[quad*4 + 3]};
    unsigned short* xo = y1 + ((size_t)(b*NF + ((f < NF) ? f : 0))*NT)*CH + quad*4;

    #pragma unroll
    for (int ti = 0; ti < 8; ti++) {
        const int t = ti*16 + c;              // B col = t within the 128-slice
        // chunk0 rows: wid + quad*2, wid + quad*2 + 1
        const int r0 = wid + quad*2;
        const uint2 dh0 = *(const uint2*)&fhi[((r0    )*128 + t)*4];
        const uint2 dh1 = *(const uint2*)&fhi[((r0 + 1)*128 + t)*4];
        const uint2 dl0 = *(const uint2*)&flo[((r0    )*128 + t)*4];
        const uint2 dl1 = *(const uint2*)&flo[((r0 + 1)*128 + t)*4];
        // chunk1 row: wid + 8 (kk = 8), quad 0 only
        uint2 dh2 = *(const uint2*)&fhi[((wid + 8)*128 + t)*4];
        uint2 dl2 = *(const uint2*)&flo[((wid + 8)*128 + t)*4];
        if (quad != 0) { dh2 = make_uint2(0u, 0u); dl2 = make_uint2(0u, 0u); }

        S8U4 Dhi0, Dlo0, Dhi1, Dlo1;
        Dhi0.u = make_uint4(dh0.x, dh0.y, dh1.x, dh1.y);
        Dlo0.u = make_uint4(dl0.x, dl0.y, dl1.x, dl1.y);
        Dhi1.u = make_uint4(dh2.x, dh2.y, 0u, 0u);
        Dlo1.u = make_uint4(dl2.x, dl2.y, 0u, 0u);

        f32x4 acc = cb;
        acc = __builtin_amdgcn_mfma_f32_16x16x32_bf16(Whi0, Dhi0.s, acc, 0, 0, 0);
        acc = __builtin_amdgcn_mfma_f32_16x16x32_bf16(Whi0, Dlo0.s, acc, 0, 0, 0);
        acc = __builtin_amdgcn_mfma_f32_16x16x32_bf16(Wlo0, Dhi0.s, acc, 0, 0, 0);
        acc = __builtin_amdgcn_mfma_f32_16x16x32_bf16(Whi1, Dhi1.s, acc, 0, 0, 0);
        acc = __builtin_amdgcn_mfma_f32_16x16x32_bf16(Whi1, Dlo1.s, acc, 0, 0, 0);
        acc = __builtin_amdgcn_mfma_f32_16x16x32_bf16(Wlo1, Dhi1.s, acc, 0, 0, 0);

        // D: row = quad*4 + r = ch, col = c = t
        const int tt = tg + t;
        if (tt < NT && f < NF) {
            float v0 = acc[0], v1 = acc[1], v2 = acc[2], v3 = acc[3];
            v0 = (v0 >= 0.f) ? v0 : al1*v0;
            v1 = (v1 >= 0.f) ? v1 : al1*v1;
            v2 = (v2 >= 0.f) ? v2 : al1*v2;
            v3 = (v3 >= 0.f) ? v3 : al1*v3;
            *(uint2*)(xo + (size_t)tt*CH) = make_uint2(pk2(v0, v1), pk2(v2, v3));
        }
    }
}

// -------------------------------------------------------------------------
// Pass 2: conv2(16->16,k5,p2) via MFMA + PReLU -> x (n,t,16).  (R9 verbatim)
// -------------------------------------------------------------------------
__global__ __launch_bounds__(256) void conv2_kernel(
    const unsigned short* __restrict__ y1,    // (b, f, t, ch) bf16
    const float* __restrict__ w2, const float* __restrict__ b2, const float* __restrict__ a2p,
    unsigned short* __restrict__ xout)
{
    __shared__ unsigned short ylds[8*128*24];    // 48 KB: [row8][t128][ch16+pad8]
    const int b    = blockIdx.x;
    const int f0   = blockIdx.y * 4;
    const int tg   = blockIdx.z * 128;
    const int tid  = threadIdx.x;
    const int wid  = tid >> 6;
    const int lane = tid & 63;

    #pragma unroll
    for (int i = 0; i < 8; i++) {
        const int idx  = tid + i*256;        // 0..2047
        const int row  = idx >> 8;           // 0..7
        const int tt   = (idx >> 1) & 127;
        const int half = idx & 1;
        const int fr   = f0 - 2 + row;
        const int gt   = tg + tt;
        uint4 v = make_uint4(0u, 0u, 0u, 0u);
        if (fr >= 0 && fr < NF && gt < NT)
            v = *(const uint4*)(y1 + ((size_t)(b*NF + fr)*NT + gt)*CH + half*8);
        *(uint4*)&ylds[(row*128 + tt)*24 + half*8] = v;
    }
    __syncthreads();

    const int c    = lane & 15;
    const int quad = lane >> 4;
    const int f    = f0 + wid;
    if (f < NF) {
        const float al2 = a2p[0];
        short8 Bh0, Bh1, Bh2, Bl0, Bl1, Bl2;
        #define MKB2(BH, BL, Q)                                                \
            { _Pragma("unroll") for (int j = 0; j < 8; j++) {                  \
                const int ci = (quad & 1)*8 + j;                               \
                const int kk = 2*(Q) + (quad >> 1);                            \
                float w = 0.f;                                                 \
                if (kk < 5) w = w2[c*80 + ci*5 + kk];                          \
                const unsigned short hb = f2bf(w);                             \
                const float hf = bf2f((short)hb);                              \
                BH[j] = (short)hb;                                             \
                BL[j] = (short)f2bf(w - hf); } }
        MKB2(Bh0, Bl0, 0); MKB2(Bh1, Bl1, 1); MKB2(Bh2, Bl2, 2);
        #undef MKB2

        // bias per ROW: acc[r] is cout = quad*4 + r
        const f32x4 cb = {b2[quad*4 + 0], b2[quad*4 + 1],
                          b2[quad*4 + 2], b2[quad*4 + 3]};
        const int ci0 = (quad & 1)*8;
        const int r0  = wid + (quad >> 1);
        unsigned short* xo = xout + ((size_t)(b*NF + f)*NT)*CH + quad*4;

        #pragma unroll
        for (int ti = 0; ti < 8; ti++) {
            const int t = ti*16 + c;             // B col = t within the 128-slice
            const int rl2 = (r0 + 4 > 7) ? 7 : (r0 + 4);
            const short8 a0 = *(const short8*)&ylds[((r0    )*128 + t)*24 + ci0];
            const short8 a1 = *(const short8*)&ylds[((r0 + 2)*128 + t)*24 + ci0];
            const short8 a2 = *(const short8*)&ylds[((rl2   )*128 + t)*24 + ci0];
            f32x4 acc = cb;
            acc = __builtin_amdgcn_mfma_f32_16x16x32_bf16(Bl0, a0, acc, 0, 0, 0);
            acc = __builtin_amdgcn_mfma_f32_16x16x32_bf16(Bl1, a1, acc, 0, 0, 0);
            acc = __builtin_amdgcn_mfma_f32_16x16x32_bf16(Bl2, a2, acc, 0, 0, 0);
            acc = __builtin_amdgcn_mfma_f32_16x16x32_bf16(Bh0, a0, acc, 0, 0, 0);
            acc = __builtin_amdgcn_mfma_f32_16x16x32_bf16(Bh1, a1, acc, 0, 0, 0);
            acc = __builtin_amdgcn_mfma_f32_16x16x32_bf16(Bh2, a2, acc, 0, 0, 0);
            const int tt = tg + t;
            if (tt < NT) {
                float v0 = acc[0], v1 = acc[1], v2 = acc[2], v3 = acc[3];
                v0 = (v0 >= 0.f) ? v0 : al2*v0;
                v1 = (v1 >= 0.f) ? v1 : al2*v1;
                v2 = (v2 >= 0.f) ? v2 : al2*v2;
                v3 = (v3 >= 0.f) ? v3 : al2*v3;
                *(uint2*)(xo + (size_t)tt*CH) = make_uint2(pk2(v0, v1), pk2(v2, v3));
            }
        }
    }
}

// -------------------------------------------------------------------------
// GRU — R10 verbatim (proven 290 us; all-register operand-swapped, zero
// LDS/barriers).  R11's in-wave dual group confirmed the wave is
// issue-port-bound: marginal cost of a 2nd group ~= full cost.  FROZEN.
// -------------------------------------------------------------------------
__global__ __launch_bounds__(64) void gru_kernel(
    const unsigned short* __restrict__ xin,  // (NSEQ, NT, 16) bf16
    const float* __restrict__ h0,    // (NSEQ, 32)
    const float* __restrict__ w_ih,  // (96, 16)
    const float* __restrict__ w_hh,  // (96, 32)
    const float* __restrict__ b_ih, const float* __restrict__ b_hh,
    const float* __restrict__ fc_w, const float* __restrict__ fc_b,
    float* __restrict__ prob,        // (NSEQ, NT)
    float* __restrict__ hout)        // (NSEQ, 32)
{
    const int lane = threadIdx.x & 63;
    const int c    = lane & 15;
    const int quad = lane >> 4;
    const int base = blockIdx.x * 16;        // 481 blocks x 16 seq
    const float L2E = 1.4426950408889634f;

    const int ub = (quad == 0) ? 16 : (quad == 1) ? 24 : (quad == 2) ? 0 : 8;
    const int cq  = c >> 2;
    const int ubr = (cq == 0) ? 16 : (cq == 1) ? 24 : (cq == 2) ? 0 : 8;
    const int uA  = ubr + (c & 3);
    const int uB  = uA + 4;

    #define BLDR(DST, CK, GROW)                                                \
        { _Pragma("unroll") for (int j = 0; j < 8; j++) {                      \
            const int k = (CK)*32 + quad*8 + j;                                \
            float wv_ = 0.f;                                                   \
            if (k < 16)      wv_ = w_ih[(GROW)*16 + k];                        \
            else if (k < 48) wv_ = w_hh[(GROW)*32 + k - 16];                   \
            DST[j] = (short)f2bf(wv_ * L2E); } }
    #define BLDX(DST, U)                                                       \
        { _Pragma("unroll") for (int j = 0; j < 8; j++) {                      \
            const int k = quad*8 + j;                                          \
            float wv_ = (k < 16) ? w_ih[(64+(U))*16 + k] : 0.f;                \
            DST[j] = (short)f2bf(wv_ * 2.f*L2E); } }
    #define BLDH(DST, CK, U)                                                   \
        { _Pragma("unroll") for (int j = 0; j < 8; j++) {                      \
            const int k = (CK)*32 + quad*8 + j;                                \
            float wv_ = (k >= 16 && k < 48) ? w_hh[(64+(U))*32 + k - 16] : 0.f;\
            DST[j] = (short)f2bf(wv_ * 2.f*L2E); } }
    #define BLDF(DST, CK)                                                      \
        { _Pragma("unroll") for (int j = 0; j < 8; j++) {                      \
            const int k = (CK)*32 + quad*8 + j;                                \
            float wv_ = (k >= 16 && k < 48) ? fc_w[k - 16] : 0.f;              \
            DST[j] = (short)f2bf(wv_); } }

    short8 WRaA, WRbA, WRaB, WRbB;
    short8 WZaA, WZbA, WZaB, WZbB;
    short8 WXaA, WXaB;
    short8 WHaA, WHbA, WHaB, WHbB;
    short8 WFa, WFb;
    BLDR(WRaA, 0, uA);     BLDR(WRbA, 1, uA);
    BLDR(WRaB, 0, uB);     BLDR(WRbB, 1, uB);
    BLDR(WZaA, 0, 32+uA);  BLDR(WZbA, 1, 32+uA);
    BLDR(WZaB, 0, 32+uB);  BLDR(WZbB, 1, 32+uB);
    BLDX(WXaA, uA);        BLDX(WXaB, uB);
    BLDH(WHaA, 0, uA);     BLDH(WHbA, 1, uA);
    BLDH(WHaB, 0, uB);     BLDH(WHbB, 1, uB);
    BLDF(WFa, 0);          BLDF(WFb, 1);

    const float4 biA = *(const float4*)(b_ih + ub);
    const float4 biB = *(const float4*)(b_ih + ub + 4);
    const float4 bhA = *(const float4*)(b_hh + ub);
    const float4 bhB = *(const float4*)(b_hh + ub + 4);
    const float4 ziA = *(const float4*)(b_ih + 32 + ub);
    const float4 ziB = *(const float4*)(b_ih + 36 + ub);
    const float4 zhA = *(const float4*)(b_hh + 32 + ub);
    const float4 zhB = *(const float4*)(b_hh + 36 + ub);
    const float4 niA = *(const float4*)(b_ih + 64 + ub);
    const float4 niB = *(const float4*)(b_ih + 68 + ub);
    const float4 nhA = *(const float4*)(b_hh + 64 + ub);
    const float4 nhB = *(const float4*)(b_hh + 68 + ub);
    const f32x4 cbRA = {(biA.x+bhA.x)*L2E, (biA.y+bhA.y)*L2E, (biA.z+bhA.z)*L2E, (biA.w+bhA.w)*L2E};
    const f32x4 cbRB = {(biB.x+bhB.x)*L2E, (biB.y+bhB.y)*L2E, (biB.z+bhB.z)*L2E, (biB.w+bhB.w)*L2E};
    const f32x4 cbZA = {(ziA.x+zhA.x)*L2E, (ziA.y+zhA.y)*L2E, (ziA.z+zhA.z)*L2E, (ziA.w+zhA.w)*L2E};
    const f32x4 cbZB = {(ziB.x+zhB.x)*L2E, (ziB.y+zhB.y)*L2E, (ziB.z+zhB.z)*L2E, (ziB.w+zhB.w)*L2E};
    const f32x4 cbXA = {niA.x*2.f*L2E, niA.y*2.f*L2E, niA.z*2.f*L2E, niA.w*2.f*L2E};
    const f32x4 cbXB = {niB.x*2.f*L2E, niB.y*2.f*L2E, niB.z*2.f*L2E, niB.w*2.f*L2E};
    const f32x4 cbHA = {nhA.x*2.f*L2E, nhA.y*2.f*L2E, nhA.z*2.f*L2E, nhA.w*2.f*L2E};
    const f32x4 cbHB = {nhB.x*2.f*L2E, nhB.y*2.f*L2E, nhB.z*2.f*L2E, nhB.w*2.f*L2E};
    const float fb = fc_b[0];
    const f32x4 cbF = {fb, fb, fb, fb};

    const float* hrow = h0 + (size_t)(base + c)*HID + ub;
    float h0_ = hrow[0], h1_ = hrow[1], h2_ = hrow[2], h3_ = hrow[3];
    float h4_ = hrow[4], h5_ = hrow[5], h6_ = hrow[6], h7_ = hrow[7];

    const unsigned short* xp = xin + ((size_t)(base + c)*NT)*CH + (quad & 1)*8;
    uint4 xcur = *(const uint4*)(xp);
    uint4 nx1  = *(const uint4*)(xp + 1*CH);
    uint4 nx2  = *(const uint4*)(xp + 2*CH);

    const short8 zero8 = {0,0,0,0,0,0,0,0};

    #define PACKH(HA)                                                          \
        { unsigned p0_, p1_, p2_, p3_;                                         \
          asm("v_cvt_pk_bf16_f32 %0, %1, %2" : "=v"(p0_) : "v"(h0_), "v"(h1_));\
          asm("v_cvt_pk_bf16_f32 %0, %1, %2" : "=v"(p1_) : "v"(h2_), "v"(h3_));\
          asm("v_cvt_pk_bf16_f32 %0, %1, %2" : "=v"(p2_) : "v"(h4_), "v"(h5_));\
          asm("v_cvt_pk_bf16_f32 %0, %1, %2" : "=v"(p3_) : "v"(h6_), "v"(h7_));\
          S8U4 hu_; hu_.u = make_uint4(p0_, p1_, p2_, p3_);                    \
          HA = hu_.s; }

    #define GS(ACR, ACZ, ACX, ACH, R, HREG)                                    \
        {                                                                      \
            const float rr = sige_(ACR[R]);                                    \
            const float zz = sige_(ACZ[R]);                                    \
            const float aa = fmaf(rr, ACH[R], ACX[R]);                         \
            const float nn = fmaf(2.f, sige_(aa), -1.f);                       \
            HREG = fmaf(zz, HREG - nn, nn);                                    \
        }

    for (int t = 0; t < NT; t++) {
        short8 ha; PACKH(ha);
        S8U4 xu; xu.u = xcur;
        const short8 a0 = (quad < 2) ? xu.s : ha;      // k0-31: x | h0-15
        const short8 a1 = (quad < 2) ? ha   : zero8;   // k32-63: h16-31 | pad

        const int tn = (t + 3 < NT) ? t + 3 : NT - 1;
        const uint4 fx = *(const uint4*)(xp + (size_t)tn*CH);

        f32x4 aRA = __builtin_amdgcn_mfma_f32_16x16x32_bf16(WRaA, a0, cbRA, 0, 0, 0);
        f32x4 aRB = __builtin_amdgcn_mfma_f32_16x16x32_bf16(WRaB, a0, cbRB, 0, 0, 0);
        f32x4 aZA = __builtin_amdgcn_mfma_f32_16x16x32_bf16(WZaA, a0, cbZA, 0, 0, 0);
        f32x4 aZB = __builtin_amdgcn_mfma_f32_16x16x32_bf16(WZaB, a0, cbZB, 0, 0, 0);
        f32x4 aXA = __builtin_amdgcn_mfma_f32_16x16x32_bf16(WXaA, a0, cbXA, 0, 0, 0);
        f32x4 aXB = __builtin_amdgcn_mfma_f32_16x16x32_bf16(WXaB, a0, cbXB, 0, 0, 0);
        f32x4 aHA = __builtin_amdgcn_mfma_f32_16x16x32_bf16(WHaA, a0, cbHA, 0, 0, 0);
        f32x4 aHB = __builtin_amdgcn_mfma_f32_16x16x32_bf16(WHaB, a0, cbHB, 0, 0, 0);
        f32x4 aF  = __builtin_amdgcn_mfma_f32_16x16x32_bf16(WFa,  a0, cbF,  0, 0, 0);
        aRA = __builtin_amdgcn_mfma_f32_16x16x32_bf16(WRbA, a1, aRA, 0, 0, 0);
        aRB = __builtin_amdgcn_mfma_f32_16x16x32_bf16(WRbB, a1, aRB, 0, 0, 0);
        aZA = __builtin_amdgcn_mfma_f32_16x16x32_bf16(WZbA, a1, aZA, 0, 0, 0);
        aZB = __builtin_amdgcn_mfma_f32_16x16x32_bf16(WZbB, a1, aZB, 0, 0, 0);
        aHA = __builtin_amdgcn_mfma_f32_16x16x32_bf16(WHbA, a1, aHA, 0, 0, 0);
        aHB = __builtin_amdgcn_mfma_f32_16x16x32_bf16(WHbB, a1, aHB, 0, 0, 0);
        aF  = __builtin_amdgcn_mfma_f32_16x16x32_bf16(WFb,  a1, aF,  0, 0, 0);

        if (t > 0 && lane < 16)
            prob[(size_t)(base + c)*NT + (t - 1)] = sig_(aF[0]);

        GS(aRA, aZA, aXA, aHA, 0, h0_);
        GS(aRA, aZA, aXA, aHA, 1, h1_);
        GS(aRA, aZA, aXA, aHA, 2, h2_);
        GS(aRA, aZA, aXA, aHA, 3, h3_);
        GS(aRB, aZB, aXB, aHB, 0, h4_);
        GS(aRB, aZB, aXB, aHB, 1, h5_);
        GS(aRB, aZB, aXB, aHB, 2, h6_);
        GS(aRB, aZB, aXB, aHB, 3, h7_);

        xcur = nx1; nx1 = nx2; nx2 = fx;
    }

    // final prob (FC on h(NT))
    {
        short8 ha; PACKH(ha);
        const short8 a0f = (quad < 2) ? zero8 : ha;
        const short8 a1f = (quad < 2) ? ha    : zero8;
        f32x4 aF = __builtin_amdgcn_mfma_f32_16x16x32_bf16(WFa, a0f, cbF, 0, 0, 0);
        aF = __builtin_amdgcn_mfma_f32_16x16x32_bf16(WFb, a1f, aF, 0, 0, 0);
        if (lane < 16)
            prob[(size_t)(base + c)*NT + (NT - 1)] = sig_(aF[0]);
    }

    float* ho = hout + (size_t)(base + c)*HID + ub;
    *(float4*)(ho)     = make_float4(h0_, h1_, h2_, h3_);
    *(float4*)(ho + 4) = make_float4(h4_, h5_, h6_, h7_);
}

// -------------------------------------------------------------------------
extern "C" void kernel_launch(void* const* d_in, const int* in_sizes, int n_in,
                              void* d_out, int out_size, void* d_ws, size_t ws_size,
                              hipStream_t stream)
{
    const float* feat = (const float*)d_in[0];
    const float* h0   = (const float*)d_in[1];
    const float* w1   = (const float*)d_in[2];
    const float* b1   = (const float*)d_in[3];
    const float* a1   = (const float*)d_in[4];
    const float* w2   = (const float*)d_in[5];
    const float* b2   = (const float*)d_in[6];
    const float* a2   = (const float*)d_in[7];
    const float* wih  = (const float*)d_in[8];
    const float* whh  = (const float*)d_in[9];
    const float* bih  = (const float*)d_in[10];
    const float* bhh  = (const float*)d_in[11];
    const float* fcw  = (const float*)d_in[12];
    const float* fcb  = (const float*)d_in[13];

    unsigned short* xbuf = (unsigned short*)d_ws;            // 123.1 MB bf16
    unsigned short* y1   = xbuf + (size_t)NSEQ*NT*CH;        // 123.1 MB bf16 (b,f,t,ch)
    float* prob = (float*)d_out;                             // (B, F, T)
    float* hout = prob + (size_t)NSEQ*NT;                    // (1, NSEQ, 32)

    dim3 c1grid(NB, 121, 4);                                 // 4 f-waves x 128 t (MFMA)
    conv1_kernel<<<c1grid, 256, 0, stream>>>(feat, w1, b1, a1, y1);
    dim3 c2grid(NB, 121, 4);                                 // 4 f x 128 t per block
    conv2_kernel<<<c2grid, 256, 0, stream>>>(y1, w2, b2, a2, xbuf);
    gru_kernel<<<NSEQ/16, 64, 0, stream>>>(xbuf, h0, wih, whh, bih, bhh, fcw, fcb, prob, hout);
}